// Round 13
// baseline (2582.516 us; speedup 1.0000x reference)
//
#include <hip/hip_runtime.h>
#include <math.h>

#define BATCH 32768
#define ISZ   256
#define HSZ   512
#define KC    768   // cell GEMM K = ISZ + HSZ

typedef __attribute__((ext_vector_type(8))) short bf16x8;
typedef __attribute__((ext_vector_type(4))) float f32x4;

// bf16 activation / weight buffers (static to avoid ws_size dependence)
static __device__ unsigned short g_xbf[(size_t)BATCH * ISZ];   // x in bf16
static __device__ unsigned short g_ha [(size_t)BATCH * HSZ];   // h0 -> h2 (bf16)
static __device__ unsigned short g_hb [(size_t)BATCH * HSZ];   // h1 (bf16)
static __device__ unsigned short g_Wc [2048 * KC];             // [Wih | Whh] bf16 [2048][768]
static __device__ unsigned short g_W1p[HSZ * HSZ];             // W1 in MFMA-fragment order
static __device__ unsigned short g_W2p[HSZ * HSZ];             // W2 in MFMA-fragment order

__device__ __forceinline__ unsigned short f2bf(float f) {
    unsigned int u = __float_as_uint(f);
    u += 0x7fff + ((u >> 16) & 1);   // RNE
    return (unsigned short)(u >> 16);
}
__device__ __forceinline__ float bf2f(unsigned short s) {
    return __uint_as_float((unsigned int)s << 16);
}
__device__ __forceinline__ float fsigm(float x) { return 1.0f / (1.0f + __expf(-x)); }
__device__ __forceinline__ float ftanh(float x) { return 1.0f - 2.0f / (__expf(2.0f * x) + 1.0f); }

__device__ __forceinline__ void gload16(const void* g, void* l) {
    __builtin_amdgcn_global_load_lds(
        (const __attribute__((address_space(1))) unsigned int*)g,
        (__attribute__((address_space(3))) unsigned int*)l, 16, 0, 0);
}

// ---------------------------------------------------------------------------
// fp32 -> bf16 conversion (float4-vectorized, row restride for Wih|Whh concat)
// DST: 0=g_xbf 1=g_ha 2=g_Wc
// ---------------------------------------------------------------------------
template <int DST>
__global__ __launch_bounds__(256) void conv_kernel(
    const float* __restrict__ src, int nv, int w4shift, int dstride, int doff)
{
    unsigned short* __restrict__ dst = DST == 0 ? g_xbf : DST == 1 ? g_ha : g_Wc;
    int i = blockIdx.x * 256 + threadIdx.x;
    const int gs = gridDim.x * 256;
    for (; i < nv; i += gs) {
        const int r = i >> w4shift;
        const int c = i & ((1 << w4shift) - 1);
        const float4 v = ((const float4*)src)[i];
        ushort4 o;
        o.x = f2bf(v.x); o.y = f2bf(v.y); o.z = f2bf(v.z); o.w = f2bf(v.w);
        *(ushort4*)&dst[(size_t)r * dstride + doff + c * 4] = o;
    }
}

// ---------------------------------------------------------------------------
// W1/W2 -> MFMA fragment order: chunk c = fb*1024 + st*64 + lq*16 + l15:
//   W'[c*8 + e] = W[fb*16+l15][st*32 + lq*8 + e]
// Fragment (fb, st) for lane l contiguous at W' + (fb*16+st)*512 + l*8 (1KB).
// ---------------------------------------------------------------------------
template <int DST>   // 0 -> g_W1p, 1 -> g_W2p
__global__ __launch_bounds__(256) void conv_fragW(const float* __restrict__ src)
{
    unsigned short* __restrict__ dst = DST == 0 ? g_W1p : g_W2p;
    const int c = blockIdx.x * 256 + threadIdx.x;   // 32768 chunks
    const int l15 = c & 15, lq = (c >> 4) & 3, st = (c >> 6) & 15, fb = c >> 10;
    const int n = fb * 16 + l15;
    const int k = st * 32 + lq * 8;
    const float4 v0 = *(const float4*)&src[(size_t)n * HSZ + k];
    const float4 v1 = *(const float4*)&src[(size_t)n * HSZ + k + 4];
    unsigned short o[8] = {f2bf(v0.x), f2bf(v0.y), f2bf(v0.z), f2bf(v0.w),
                           f2bf(v1.x), f2bf(v1.y), f2bf(v1.z), f2bf(v1.w)};
    *(bf16x8*)&dst[(size_t)c * 8] = *(bf16x8*)o;
}

// ---------------------------------------------------------------------------
// LSTM cell MFMA GEMM (R4-R12 structure): 128x128 tile, BK=64, 4 waves,
// dbuf LDS, counted vmcnt(8), bijective XCD swizzle (n-fast).
// MODE 0: h1 -> g_hb (bf16).  MODE 1: h2 -> g_ha (bf16 ONLY; fp32 copy gone).
// ---------------------------------------------------------------------------
template <int MODE>
__global__ __launch_bounds__(256) void cell_kernel(
    const float* __restrict__ bih, const float* __restrict__ bhh,
    const float* __restrict__ c_in, float* __restrict__ c_out)
{
    constexpr int NKT = KC / 64;
    constexpr int NCH = 16;

    __shared__ __align__(16) unsigned short As[2][128 * 64];
    __shared__ __align__(16) unsigned short Bs[2][128 * 64];

    const int orig = blockIdx.x;
    const int q = gridDim.x >> 3;
    const int wg = (orig & 7) * q + (orig >> 3);
    const int nbc = wg % NCH;
    const int mBase = (wg / NCH) * 128;

    const int tid  = threadIdx.x;
    const int lane = tid & 63;
    const int wid  = tid >> 6;
    const int wr   = wid >> 1, wc = wid & 1;
    const int l15  = lane & 15, lq = lane >> 4;

    const unsigned short* __restrict__ Ah = (MODE == 0) ? g_ha : g_hb;

    const int arow = tid >> 3, ch = tid & 7;
    int bgrow[4];
#pragma unroll
    for (int j = 0; j < 4; ++j) {
        const int vr = j * 32 + arow;
        const int g    = (vr >> 4) & 3;
        const int jcol = nbc * 32 + (vr >> 6) * 16 + (vr & 15);
        bgrow[j] = g * 512 + jcol;
    }

    auto stage = [&](int buf, int kt) {
        const int k0 = kt * 64;
#pragma unroll
        for (int j = 0; j < 4; ++j) {
            const int row = j * 32 + arow;
            const unsigned short* ga = (k0 < 256)
                ? g_xbf + (size_t)(mBase + row) * ISZ + (k0       + ch * 8)
                : Ah    + (size_t)(mBase + row) * HSZ + (k0 - 256 + ch * 8);
            gload16(ga, (char*)As[buf] + j * 4096 + wid * 1024);
            const unsigned short* gb = g_Wc + (size_t)bgrow[j] * KC + k0 + ch * 8;
            gload16(gb, (char*)Bs[buf] + j * 4096 + wid * 1024);
        }
    };

    f32x4 acc[4][4];
#pragma unroll
    for (int fm = 0; fm < 4; ++fm)
#pragma unroll
        for (int fn = 0; fn < 4; ++fn) acc[fm][fn] = (f32x4){0.f, 0.f, 0.f, 0.f};

    stage(0, 0);
    int cur = 0;
    for (int kt = 0; kt < NKT; ++kt) {
        if (kt + 1 < NKT) {
            stage(cur ^ 1, kt + 1);
            asm volatile("s_waitcnt vmcnt(8)" ::: "memory");
        } else {
            asm volatile("s_waitcnt vmcnt(0)" ::: "memory");
        }
        asm volatile("s_barrier" ::: "memory");
#pragma unroll
        for (int kk = 0; kk < 2; ++kk) {
            bf16x8 a[4], b[4];
#pragma unroll
            for (int f = 0; f < 4; ++f) {
                const int rowA = wr * 64 + f * 16 + l15;
                a[f] = *(const bf16x8*)((const char*)As[cur] + rowA * 128 + kk * 64 + lq * 16);
                const int rowB = wc * 64 + f * 16 + l15;
                b[f] = *(const bf16x8*)((const char*)Bs[cur] + rowB * 128 + kk * 64 + lq * 16);
            }
#pragma unroll
            for (int fm = 0; fm < 4; ++fm)
#pragma unroll
                for (int fn = 0; fn < 4; ++fn)
                    acc[fm][fn] = __builtin_amdgcn_mfma_f32_16x16x32_bf16(
                        a[fm], b[fn], acc[fm][fn], 0, 0, 0);
        }
        asm volatile("s_barrier" ::: "memory");
        cur ^= 1;
    }

    const int j = nbc * 32 + wc * 16 + l15;
    float bsum[4];
#pragma unroll
    for (int g = 0; g < 4; ++g) bsum[g] = bih[g * 512 + j] + bhh[g * 512 + j];
#pragma unroll
    for (int fm = 0; fm < 4; ++fm) {
#pragma unroll
        for (int r = 0; r < 4; ++r) {
            const int m = mBase + wr * 64 + fm * 16 + lq * 4 + r;
            const size_t idx = (size_t)m * HSZ + j;
            const float ig = fsigm(acc[fm][0][r] + bsum[0]);
            const float fg = fsigm(acc[fm][1][r] + bsum[1]);
            const float gg = ftanh(acc[fm][2][r] + bsum[2]);
            const float og = fsigm(acc[fm][3][r] + bsum[3]);
            const float cnew = fg * c_in[idx] + ig * gg;
            const float hnew = og * ftanh(cnew);
            c_out[idx] = cnew;
            if constexpr (MODE == 0) g_hb[idx] = f2bf(hnew);
            else                     g_ha[idx] = f2bf(hnew);
        }
    }
}

// ---------------------------------------------------------------------------
// Fully-fused RK4, v9. Block = 32 rows x 512 threads (8 waves), wave owns
// 32x64 (2 m-frags x 4 n-frags).
// NEW: (a) W staged in HALF-steps (2 frags) into per-wave 3-buffer sW via
// global_load_lds + steady vmcnt(4) -> prefetch distance 2 half-steps;
// (b) no sH / no g_h2f: h2 kept bf16-packed in 16 regs per thread, sU seeded
// from g_ha; (c) LDS = 32KB(sU) + 48KB(sW) = 80KB -> 2 blocks/CU,
// 4 waves/SIMD; live regs ~110 < 128 cap -> no spill; (d) setprio on MFMA.
// ---------------------------------------------------------------------------
__global__ __launch_bounds__(512, 1) void rk_fused_kernel(
    const float* __restrict__ ts, const float* __restrict__ b1,
    const float* __restrict__ b2, float* __restrict__ out_ht)
{
    __shared__ __align__(16) unsigned short sU[32 * 512];       // 32 KB
    __shared__ __align__(16) unsigned short sW[8 * 3 * 1024];   // 48 KB: [wave][3 bufs][2KB]

    const int tid = threadIdx.x, lane = tid & 63;
    const int w = tid >> 6;                  // wave -> 64-col chunk
    const int l15 = lane & 15, lq = lane >> 4;
    const int nb = w * 64;
    const int m0 = blockIdx.x * 32;

    float b1v[4], b2v[4];
#pragma unroll
    for (int fn = 0; fn < 4; ++fn) {
        b1v[fn] = b1[nb + fn * 16 + l15];
        b2v[fn] = b2[nb + fn * 16 + l15];
    }

    // seed sU (htmp = h2, bf16) from g_ha with 16B chunks, swizzled
    {
#pragma unroll
        for (int i = 0; i < 4; ++i) {
            const int flat = i * 512 + tid;       // 16B-chunk index in 32x512
            const int row = flat >> 6;            // 64 chunks per row
            const int c16 = flat & 63;
            const uint4 v = *(const uint4*)(g_ha + (size_t)(m0 + row) * HSZ + c16 * 8);
            *(uint4*)((char*)sU + row * 1024 + ((c16 * 16) ^ ((row & 7) << 4))) = v;
        }
    }

    // h2 slice in packed bf16 regs: h2p[fm][fn][rr] = rows (lq*4+rr*2, +1), col nb+fn*16+l15
    unsigned int h2p[2][4][2];
#pragma unroll
    for (int fm = 0; fm < 2; ++fm)
#pragma unroll
        for (int fn = 0; fn < 4; ++fn)
#pragma unroll
            for (int rr = 0; rr < 2; ++rr) {
                const int col = nb + fn * 16 + l15;
                const unsigned int lo = g_ha[(size_t)(m0 + fm * 16 + lq * 4 + rr * 2)     * HSZ + col];
                const unsigned int hi = g_ha[(size_t)(m0 + fm * 16 + lq * 4 + rr * 2 + 1) * HSZ + col];
                h2p[fm][fn][rr] = lo | (hi << 16);
            }
    asm volatile("s_waitcnt vmcnt(0)" ::: "memory");   // drain init loads (clean vmcnt)
    __syncthreads();

    f32x4 rk[2][4];
#pragma unroll
    for (int fm = 0; fm < 2; ++fm)
#pragma unroll
        for (int fn = 0; fn < 4; ++fn) rk[fm][fn] = (f32x4){0.f, 0.f, 0.f, 0.f};

    char* const sWme = (char*)sW + w * 6144;   // 3 bufs x 2KB

    // stage half-step hh (2 fragments) into buf hh%3
    auto stage_half = [&](const unsigned short* __restrict__ Wp, int hh) {
        const int st = hh >> 1, half = hh & 1, buf = hh % 3;
#pragma unroll
        for (int f = 0; f < 2; ++f) {
            const int fb = w * 4 + half * 2 + f;
            const unsigned short* g = Wp + (size_t)((fb * 16 + st) * 512) + lane * 8;
            gload16(g, sWme + buf * 2048 + f * 1024);
        }
    };
    auto loadA = [&](bf16x8 (&aa)[2], int st) {
#pragma unroll
        for (int f = 0; f < 2; ++f) {
            const int row = f * 16 + l15;
            aa[f] = *(const bf16x8*)((const char*)sU + row * 1024 +
                                     ((st * 64 + lq * 16) ^ ((l15 & 7) << 4)));
        }
    };

    auto do_gemm = [&](const unsigned short* __restrict__ Wp, f32x4 (&gacc)[2][4]) {
#pragma unroll
        for (int fm = 0; fm < 2; ++fm)
#pragma unroll
            for (int fn = 0; fn < 4; ++fn) gacc[fm][fn] = (f32x4){0.f, 0.f, 0.f, 0.f};
        stage_half(Wp, 0);
        stage_half(Wp, 1);
        bf16x8 a[2];
#pragma unroll 1
        for (int hh = 0; hh < 32; ++hh) {
            if (hh < 30) {
                stage_half(Wp, hh + 2);
                asm volatile("s_waitcnt vmcnt(4)" ::: "memory");
            } else if (hh == 30) {
                asm volatile("s_waitcnt vmcnt(2)" ::: "memory");
            } else {
                asm volatile("s_waitcnt vmcnt(0)" ::: "memory");
            }
            if (!(hh & 1)) loadA(a, hh >> 1);
            const char* bp = sWme + (hh % 3) * 2048;
            bf16x8 bfr0 = *(const bf16x8*)(bp + lane * 16);
            bf16x8 bfr1 = *(const bf16x8*)(bp + 1024 + lane * 16);
            const int f0 = (hh & 1) * 2;
            __builtin_amdgcn_s_setprio(1);
#pragma unroll
            for (int fm = 0; fm < 2; ++fm) {
                gacc[fm][f0]     = __builtin_amdgcn_mfma_f32_16x16x32_bf16(
                    a[fm], bfr0, gacc[fm][f0], 0, 0, 0);
                gacc[fm][f0 + 1] = __builtin_amdgcn_mfma_f32_16x16x32_bf16(
                    a[fm], bfr1, gacc[fm][f0 + 1], 0, 0, 0);
            }
            __builtin_amdgcn_s_setprio(0);
        }
    };

#pragma unroll 1
    for (int s = 0; s < 4; ++s) {
        f32x4 gacc[2][4];
        // GEMM1: u = tanh(htmp @ W1^T + b1)
        do_gemm(g_W1p, gacc);
        __syncthreads();                      // all htmp reads complete
#pragma unroll
        for (int fm = 0; fm < 2; ++fm)
#pragma unroll
            for (int fn = 0; fn < 4; ++fn)
#pragma unroll
                for (int r = 0; r < 4; ++r) {
                    const int row = fm * 16 + lq * 4 + r;
                    const int col = nb + fn * 16 + l15;
                    *(unsigned short*)((char*)sU + row * 1024 +
                                       ((col * 2) ^ ((row & 7) << 4))) =
                        f2bf(ftanh(gacc[fm][fn][r] + b1v[fn]));
                }
        __syncthreads();
        // GEMM2: k = u @ W2^T + b2
        do_gemm(g_W2p, gacc);
        __syncthreads();                      // all u reads complete
        const float wk = (s == 1 || s == 2) ? 2.0f : 1.0f;
        const float cs = (s == 2) ? 1.0f : 0.5f;
#pragma unroll
        for (int fm = 0; fm < 2; ++fm) {
            float dtf[4];
#pragma unroll
            for (int r = 0; r < 4; ++r) {
                const int m = m0 + fm * 16 + lq * 4 + r;
                const float2 tv = *(const float2*)&ts[2 * m];
                dtf[r] = tv.y - tv.x;
            }
#pragma unroll
            for (int fn = 0; fn < 4; ++fn)
#pragma unroll
                for (int r = 0; r < 4; ++r) {
                    const int row = fm * 16 + lq * 4 + r;
                    const int col = nb + fn * 16 + l15;
                    const float kv = gacc[fm][fn][r] + b2v[fn];
                    rk[fm][fn][r] += wk * kv;
                    const float h2 = bf2f((unsigned short)
                        (h2p[fm][fn][r >> 1] >> ((r & 1) * 16)));
                    if (s < 3) {
                        const int off = row * 1024 + ((col * 2) ^ ((row & 7) << 4));
                        *(unsigned short*)((char*)sU + off) = f2bf(h2 + cs * dtf[r] * kv);
                    } else {
                        out_ht[(size_t)(m0 + row) * HSZ + col] =
                            h2 + dtf[r] * (1.0f / 6.0f) * rk[fm][fn][r];
                    }
                }
        }
        if (s < 3) __syncthreads();
    }
}

extern "C" void kernel_launch(void* const* d_in, const int* in_sizes, int n_in,
                              void* d_out, int out_size, void* d_ws, size_t ws_size,
                              hipStream_t stream) {
    const float* x   = (const float*)d_in[0];
    const float* h0  = (const float*)d_in[1];
    const float* c0  = (const float*)d_in[2];
    const float* ts  = (const float*)d_in[3];
    const float* Wih = (const float*)d_in[4];
    const float* Whh = (const float*)d_in[5];
    const float* bih = (const float*)d_in[6];
    const float* bhh = (const float*)d_in[7];
    const float* W1  = (const float*)d_in[8];
    const float* b1  = (const float*)d_in[9];
    const float* W2  = (const float*)d_in[10];
    const float* b2  = (const float*)d_in[11];

    float* out_ht = (float*)d_out;
    float* out_c  = out_ht + (size_t)BATCH * HSZ;

    dim3 blk(256);
    conv_kernel<0><<<2048, blk, 0, stream>>>(x,   BATCH * ISZ / 4, 6, ISZ, 0);
    conv_kernel<1><<<2048, blk, 0, stream>>>(h0,  BATCH * HSZ / 4, 7, HSZ, 0);
    conv_kernel<2><<<256,  blk, 0, stream>>>(Wih, 2048 * 256 / 4,  6, KC, 0);
    conv_kernel<2><<<256,  blk, 0, stream>>>(Whh, 2048 * 512 / 4,  7, KC, 256);
    conv_fragW<0><<<128,  blk, 0, stream>>>(W1);
    conv_fragW<1><<<128,  blk, 0, stream>>>(W2);

    dim3 gcell(BATCH / 128 * 16);  // 4096 blocks: 16 n-chunks x 256 m-panels

    cell_kernel<0><<<gcell, blk, 0, stream>>>(bih, bhh, c0,    out_c);
    cell_kernel<1><<<gcell, blk, 0, stream>>>(bih, bhh, out_c, out_c);

    rk_fused_kernel<<<BATCH / 32, 512, 0, stream>>>(ts, b1, b2, out_ht);
}

// Round 14
// 821.345 us; speedup vs baseline: 3.1443x; 3.1443x over previous
//
#include <hip/hip_runtime.h>
#include <math.h>

#define BATCH 32768
#define ISZ   256
#define HSZ   512
#define KC    768   // cell GEMM K = ISZ + HSZ

typedef __attribute__((ext_vector_type(8))) short bf16x8;
typedef __attribute__((ext_vector_type(4))) float f32x4;

// bf16 activation / weight buffers (static to avoid ws_size dependence)
static __device__ unsigned short g_xbf[(size_t)BATCH * ISZ];   // x in bf16
static __device__ unsigned short g_ha [(size_t)BATCH * HSZ];   // h0 (bf16)
static __device__ unsigned short g_hb [(size_t)BATCH * HSZ];   // h1 (bf16)
static __device__ float          g_h2f[(size_t)BATCH * HSZ];   // new_h fp32
static __device__ unsigned short g_Wc [2048 * KC];             // [Wih | Whh] bf16 [2048][768]
static __device__ unsigned short g_W1p[HSZ * HSZ];             // W1 in MFMA-fragment order
static __device__ unsigned short g_W2p[HSZ * HSZ];             // W2 in MFMA-fragment order

__device__ __forceinline__ unsigned short f2bf(float f) {
    unsigned int u = __float_as_uint(f);
    u += 0x7fff + ((u >> 16) & 1);   // RNE
    return (unsigned short)(u >> 16);
}
__device__ __forceinline__ float bf2f(unsigned short s) {
    return __uint_as_float((unsigned int)s << 16);
}
__device__ __forceinline__ float fsigm(float x) { return 1.0f / (1.0f + __expf(-x)); }
__device__ __forceinline__ float ftanh(float x) { return 1.0f - 2.0f / (__expf(2.0f * x) + 1.0f); }

__device__ __forceinline__ void gload16(const void* g, void* l) {
    __builtin_amdgcn_global_load_lds(
        (const __attribute__((address_space(1))) unsigned int*)g,
        (__attribute__((address_space(3))) unsigned int*)l, 16, 0, 0);
}

// ---------------------------------------------------------------------------
// fp32 -> bf16 conversion (float4-vectorized, row restride for Wih|Whh concat)
// DST: 0=g_xbf 1=g_ha 2=g_Wc
// ---------------------------------------------------------------------------
template <int DST>
__global__ __launch_bounds__(256) void conv_kernel(
    const float* __restrict__ src, int nv, int w4shift, int dstride, int doff)
{
    unsigned short* __restrict__ dst = DST == 0 ? g_xbf : DST == 1 ? g_ha : g_Wc;
    int i = blockIdx.x * 256 + threadIdx.x;
    const int gs = gridDim.x * 256;
    for (; i < nv; i += gs) {
        const int r = i >> w4shift;
        const int c = i & ((1 << w4shift) - 1);
        const float4 v = ((const float4*)src)[i];
        ushort4 o;
        o.x = f2bf(v.x); o.y = f2bf(v.y); o.z = f2bf(v.z); o.w = f2bf(v.w);
        *(ushort4*)&dst[(size_t)r * dstride + doff + c * 4] = o;
    }
}

// ---------------------------------------------------------------------------
// W1/W2 -> MFMA fragment order: chunk c = fb*1024 + st*64 + lq*16 + l15:
//   W'[c*8 + e] = W[fb*16+l15][st*32 + lq*8 + e]
// Fragment (fb, st) for lane l contiguous at W' + (fb*16+st)*512 + l*8 (1KB).
// ---------------------------------------------------------------------------
template <int DST>   // 0 -> g_W1p, 1 -> g_W2p
__global__ __launch_bounds__(256) void conv_fragW(const float* __restrict__ src)
{
    unsigned short* __restrict__ dst = DST == 0 ? g_W1p : g_W2p;
    const int c = blockIdx.x * 256 + threadIdx.x;   // 32768 chunks
    const int l15 = c & 15, lq = (c >> 4) & 3, st = (c >> 6) & 15, fb = c >> 10;
    const int n = fb * 16 + l15;
    const int k = st * 32 + lq * 8;
    const float4 v0 = *(const float4*)&src[(size_t)n * HSZ + k];
    const float4 v1 = *(const float4*)&src[(size_t)n * HSZ + k + 4];
    unsigned short o[8] = {f2bf(v0.x), f2bf(v0.y), f2bf(v0.z), f2bf(v0.w),
                           f2bf(v1.x), f2bf(v1.y), f2bf(v1.z), f2bf(v1.w)};
    *(bf16x8*)&dst[(size_t)c * 8] = *(bf16x8*)o;
}

// ---------------------------------------------------------------------------
// LSTM cell MFMA GEMM (R4-R11 structure, unchanged): 128x128 tile, BK=64,
// 4 waves, dbuf LDS, counted vmcnt(8), bijective XCD swizzle (n-fast).
// MODE 0: h1 -> g_hb (bf16).  MODE 1: h2 -> g_h2f (fp32).
// ---------------------------------------------------------------------------
template <int MODE>
__global__ __launch_bounds__(256) void cell_kernel(
    const float* __restrict__ bih, const float* __restrict__ bhh,
    const float* __restrict__ c_in, float* __restrict__ c_out)
{
    constexpr int NKT = KC / 64;
    constexpr int NCH = 16;

    __shared__ __align__(16) unsigned short As[2][128 * 64];
    __shared__ __align__(16) unsigned short Bs[2][128 * 64];

    const int orig = blockIdx.x;
    const int q = gridDim.x >> 3;
    const int wg = (orig & 7) * q + (orig >> 3);
    const int nbc = wg % NCH;
    const int mBase = (wg / NCH) * 128;

    const int tid  = threadIdx.x;
    const int lane = tid & 63;
    const int wid  = tid >> 6;
    const int wr   = wid >> 1, wc = wid & 1;
    const int l15  = lane & 15, lq = lane >> 4;

    const unsigned short* __restrict__ Ah = (MODE == 0) ? g_ha : g_hb;

    const int arow = tid >> 3, ch = tid & 7;
    int bgrow[4];
#pragma unroll
    for (int j = 0; j < 4; ++j) {
        const int vr = j * 32 + arow;
        const int g    = (vr >> 4) & 3;
        const int jcol = nbc * 32 + (vr >> 6) * 16 + (vr & 15);
        bgrow[j] = g * 512 + jcol;
    }

    auto stage = [&](int buf, int kt) {
        const int k0 = kt * 64;
#pragma unroll
        for (int j = 0; j < 4; ++j) {
            const int row = j * 32 + arow;
            const unsigned short* ga = (k0 < 256)
                ? g_xbf + (size_t)(mBase + row) * ISZ + (k0       + ch * 8)
                : Ah    + (size_t)(mBase + row) * HSZ + (k0 - 256 + ch * 8);
            gload16(ga, (char*)As[buf] + j * 4096 + wid * 1024);
            const unsigned short* gb = g_Wc + (size_t)bgrow[j] * KC + k0 + ch * 8;
            gload16(gb, (char*)Bs[buf] + j * 4096 + wid * 1024);
        }
    };

    f32x4 acc[4][4];
#pragma unroll
    for (int fm = 0; fm < 4; ++fm)
#pragma unroll
        for (int fn = 0; fn < 4; ++fn) acc[fm][fn] = (f32x4){0.f, 0.f, 0.f, 0.f};

    stage(0, 0);
    int cur = 0;
    for (int kt = 0; kt < NKT; ++kt) {
        if (kt + 1 < NKT) {
            stage(cur ^ 1, kt + 1);
            asm volatile("s_waitcnt vmcnt(8)" ::: "memory");
        } else {
            asm volatile("s_waitcnt vmcnt(0)" ::: "memory");
        }
        asm volatile("s_barrier" ::: "memory");
#pragma unroll
        for (int kk = 0; kk < 2; ++kk) {
            bf16x8 a[4], b[4];
#pragma unroll
            for (int f = 0; f < 4; ++f) {
                const int rowA = wr * 64 + f * 16 + l15;
                a[f] = *(const bf16x8*)((const char*)As[cur] + rowA * 128 + kk * 64 + lq * 16);
                const int rowB = wc * 64 + f * 16 + l15;
                b[f] = *(const bf16x8*)((const char*)Bs[cur] + rowB * 128 + kk * 64 + lq * 16);
            }
#pragma unroll
            for (int fm = 0; fm < 4; ++fm)
#pragma unroll
                for (int fn = 0; fn < 4; ++fn)
                    acc[fm][fn] = __builtin_amdgcn_mfma_f32_16x16x32_bf16(
                        a[fm], b[fn], acc[fm][fn], 0, 0, 0);
        }
        asm volatile("s_barrier" ::: "memory");
        cur ^= 1;
    }

    const int j = nbc * 32 + wc * 16 + l15;
    float bsum[4];
#pragma unroll
    for (int g = 0; g < 4; ++g) bsum[g] = bih[g * 512 + j] + bhh[g * 512 + j];
#pragma unroll
    for (int fm = 0; fm < 4; ++fm) {
#pragma unroll
        for (int r = 0; r < 4; ++r) {
            const int m = mBase + wr * 64 + fm * 16 + lq * 4 + r;
            const size_t idx = (size_t)m * HSZ + j;
            const float ig = fsigm(acc[fm][0][r] + bsum[0]);
            const float fg = fsigm(acc[fm][1][r] + bsum[1]);
            const float gg = ftanh(acc[fm][2][r] + bsum[2]);
            const float og = fsigm(acc[fm][3][r] + bsum[3]);
            const float cnew = fg * c_in[idx] + ig * gg;
            const float hnew = og * ftanh(cnew);
            c_out[idx] = cnew;
            if constexpr (MODE == 0) g_hb[idx] = f2bf(hnew);
            else                     g_h2f[idx] = hnew;
        }
    }
}

// ---------------------------------------------------------------------------
// Fully-fused RK4, v10 = R11 structure (proven: VGPR 128, no spill, rk=325us)
// with ONE change: W register-prefetch deepened from 1 full-step (b0/b1) to
// 4 static HALF-step buffers bA..bD, consumed in a x4-unrolled slot loop with
// sched_barrier(0) per slot (R9-proven anti-hoist). Same 32 VGPRs of buffer,
// ~3x the issue->use distance -> covers ~225cy L2 latency at 4 waves/SIMD.
// setprio(1) around each 4-MFMA cluster (T5; schedule now phase-split).
// Block = 32 rows x 512 threads (8 waves), wave owns 32x64.
// LDS: sU 32KB (htmp/u, XOR-swizzled) + sH 32KB (h2 bf16).
// ---------------------------------------------------------------------------
__global__ __launch_bounds__(512, 1) void rk_fused_kernel(
    const float* __restrict__ ts, const float* __restrict__ b1,
    const float* __restrict__ b2, float* __restrict__ out_ht)
{
    __shared__ __align__(16) unsigned short sU[32 * 512];   // 32 KB
    __shared__ __align__(16) unsigned short sH[32 * 512];   // 32 KB

    const int tid = threadIdx.x, lane = tid & 63;
    const int w = tid >> 6;                  // wave -> 64-col chunk
    const int l15 = lane & 15, lq = lane >> 4;
    const int nb = w * 64;
    const int m0 = blockIdx.x * 32;

    float b1v[4], b2v[4];
#pragma unroll
    for (int fn = 0; fn < 4; ++fn) {
        b1v[fn] = b1[nb + fn * 16 + l15];
        b2v[fn] = b2[nb + fn * 16 + l15];
    }

    // init: coalesced float4 read of h2, seed sU (htmp) and sH (h2 bf16)
    {
        const float4* __restrict__ src = (const float4*)(g_h2f + (size_t)m0 * HSZ);
#pragma unroll
        for (int i = 0; i < 8; ++i) {
            const int flat = i * 512 + tid;       // float4 index in 32x128
            const int row = flat >> 7;
            const int c4 = flat & 127;
            const float4 v = src[flat];
            ushort4 o;
            o.x = f2bf(v.x); o.y = f2bf(v.y); o.z = f2bf(v.z); o.w = f2bf(v.w);
            const int off = row * 1024 + ((c4 * 8) ^ ((row & 7) << 4));
            *(ushort4*)((char*)sU + off) = o;
            *(ushort4*)((char*)sH + off) = o;
        }
    }
    __syncthreads();

    f32x4 rk[2][4];
#pragma unroll
    for (int fm = 0; fm < 2; ++fm)
#pragma unroll
        for (int fn = 0; fn < 4; ++fn) rk[fm][fn] = (f32x4){0.f, 0.f, 0.f, 0.f};

    // half-step W fragment loader: half hh covers fn = {(hh&1)*2, (hh&1)*2+1}
    auto loadBH = [&](bf16x8 (&bb)[2], const unsigned short* __restrict__ Wp, int hh) {
        const int st = hh >> 1, half = hh & 1;
#pragma unroll
        for (int f = 0; f < 2; ++f)
            bb[f] = *(const bf16x8*)(
                Wp + (size_t)(((w * 4 + half * 2 + f) * 16 + st) * 512 + lane * 8));
    };
    auto loadA = [&](bf16x8 (&aa)[2], int st) {
#pragma unroll
        for (int f = 0; f < 2; ++f) {
            const int row = f * 16 + l15;
            aa[f] = *(const bf16x8*)((const char*)sU + row * 1024 +
                                     ((st * 64 + lq * 16) ^ ((l15 & 7) << 4)));
        }
    };

#define MFMA4(BB, F0)                                                          \
    __builtin_amdgcn_s_setprio(1);                                             \
    _Pragma("unroll")                                                          \
    for (int fm = 0; fm < 2; ++fm) {                                           \
        gacc[fm][F0]     = __builtin_amdgcn_mfma_f32_16x16x32_bf16(            \
            a[fm], BB[0], gacc[fm][F0], 0, 0, 0);                              \
        gacc[fm][F0 + 1] = __builtin_amdgcn_mfma_f32_16x16x32_bf16(            \
            a[fm], BB[1], gacc[fm][F0 + 1], 0, 0, 0);                          \
    }                                                                          \
    __builtin_amdgcn_s_setprio(0);

    auto do_gemm = [&](const unsigned short* __restrict__ Wp, f32x4 (&gacc)[2][4]) {
#pragma unroll
        for (int fm = 0; fm < 2; ++fm)
#pragma unroll
            for (int fn = 0; fn < 4; ++fn) gacc[fm][fn] = (f32x4){0.f, 0.f, 0.f, 0.f};
        bf16x8 bA[2], bB[2], bC[2], bD[2], a[2];
        loadBH(bA, Wp, 0);
        loadBH(bB, Wp, 1);
        loadBH(bC, Wp, 2);
        loadBH(bD, Wp, 3);
#pragma unroll 1
        for (int i = 0; i < 8; ++i) {
            const int hh = i * 4;
            // slot 0: consume bA (half hh, even -> new a, fn {0,1})
            loadA(a, hh >> 1);
            MFMA4(bA, 0)
            if (i < 7) loadBH(bA, Wp, hh + 4);
            __builtin_amdgcn_sched_barrier(0);
            // slot 1: consume bB (half hh+1, odd -> same a, fn {2,3})
            MFMA4(bB, 2)
            if (i < 7) loadBH(bB, Wp, hh + 5);
            __builtin_amdgcn_sched_barrier(0);
            // slot 2: consume bC (half hh+2, even -> new a)
            loadA(a, (hh + 2) >> 1);
            MFMA4(bC, 0)
            if (i < 7) loadBH(bC, Wp, hh + 6);
            __builtin_amdgcn_sched_barrier(0);
            // slot 3: consume bD (half hh+3, odd)
            MFMA4(bD, 2)
            if (i < 7) loadBH(bD, Wp, hh + 7);
            __builtin_amdgcn_sched_barrier(0);
        }
    };

#pragma unroll 1
    for (int s = 0; s < 4; ++s) {
        f32x4 gacc[2][4];
        // GEMM1: u = tanh(htmp @ W1^T + b1)
        do_gemm(g_W1p, gacc);
        __syncthreads();                      // htmp reads complete
#pragma unroll
        for (int fm = 0; fm < 2; ++fm)
#pragma unroll
            for (int fn = 0; fn < 4; ++fn)
#pragma unroll
                for (int r = 0; r < 4; ++r) {
                    const int row = fm * 16 + lq * 4 + r;
                    const int col = nb + fn * 16 + l15;
                    *(unsigned short*)((char*)sU + row * 1024 +
                                       ((col * 2) ^ ((row & 7) << 4))) =
                        f2bf(ftanh(gacc[fm][fn][r] + b1v[fn]));
                }
        __syncthreads();
        // GEMM2: k = u @ W2^T + b2
        do_gemm(g_W2p, gacc);
        __syncthreads();                      // u reads complete
        const float wk = (s == 1 || s == 2) ? 2.0f : 1.0f;
        const float cs = (s == 2) ? 1.0f : 0.5f;
#pragma unroll
        for (int fm = 0; fm < 2; ++fm) {
            float dtf[4];
#pragma unroll
            for (int r = 0; r < 4; ++r) {
                const int m = m0 + fm * 16 + lq * 4 + r;
                const float2 tv = *(const float2*)&ts[2 * m];
                dtf[r] = tv.y - tv.x;
            }
#pragma unroll
            for (int fn = 0; fn < 4; ++fn)
#pragma unroll
                for (int r = 0; r < 4; ++r) {
                    const int row = fm * 16 + lq * 4 + r;
                    const int col = nb + fn * 16 + l15;
                    const float kv = gacc[fm][fn][r] + b2v[fn];
                    rk[fm][fn][r] += wk * kv;
                    if (s < 3) {
                        const int off = row * 1024 + ((col * 2) ^ ((row & 7) << 4));
                        const float h2 = bf2f(*(const unsigned short*)((const char*)sH + off));
                        *(unsigned short*)((char*)sU + off) = f2bf(h2 + cs * dtf[r] * kv);
                    } else {
                        const size_t idx = (size_t)(m0 + row) * HSZ + col;
                        out_ht[idx] = g_h2f[idx] + dtf[r] * (1.0f / 6.0f) * rk[fm][fn][r];
                    }
                }
        }
        if (s < 3) __syncthreads();
    }
#undef MFMA4
}

extern "C" void kernel_launch(void* const* d_in, const int* in_sizes, int n_in,
                              void* d_out, int out_size, void* d_ws, size_t ws_size,
                              hipStream_t stream) {
    const float* x   = (const float*)d_in[0];
    const float* h0  = (const float*)d_in[1];
    const float* c0  = (const float*)d_in[2];
    const float* ts  = (const float*)d_in[3];
    const float* Wih = (const float*)d_in[4];
    const float* Whh = (const float*)d_in[5];
    const float* bih = (const float*)d_in[6];
    const float* bhh = (const float*)d_in[7];
    const float* W1  = (const float*)d_in[8];
    const float* b1  = (const float*)d_in[9];
    const float* W2  = (const float*)d_in[10];
    const float* b2  = (const float*)d_in[11];

    float* out_ht = (float*)d_out;
    float* out_c  = out_ht + (size_t)BATCH * HSZ;

    dim3 blk(256);
    conv_kernel<0><<<2048, blk, 0, stream>>>(x,   BATCH * ISZ / 4, 6, ISZ, 0);
    conv_kernel<1><<<2048, blk, 0, stream>>>(h0,  BATCH * HSZ / 4, 7, HSZ, 0);
    conv_kernel<2><<<256,  blk, 0, stream>>>(Wih, 2048 * 256 / 4,  6, KC, 0);
    conv_kernel<2><<<256,  blk, 0, stream>>>(Whh, 2048 * 512 / 4,  7, KC, 256);
    conv_fragW<0><<<128,  blk, 0, stream>>>(W1);
    conv_fragW<1><<<128,  blk, 0, stream>>>(W2);

    dim3 gcell(BATCH / 128 * 16);  // 4096 blocks: 16 n-chunks x 256 m-panels

    cell_kernel<0><<<gcell, blk, 0, stream>>>(bih, bhh, c0,    out_c);
    cell_kernel<1><<<gcell, blk, 0, stream>>>(bih, bhh, out_c, out_c);

    rk_fused_kernel<<<BATCH / 32, 512, 0, stream>>>(ts, b1, b2, out_ht);
}

// Round 15
// 749.437 us; speedup vs baseline: 3.4459x; 1.0960x over previous
//
#include <hip/hip_runtime.h>
#include <math.h>

#define BATCH 32768
#define ISZ   256
#define HSZ   512
#define KC    768   // cell GEMM K = ISZ + HSZ

typedef __attribute__((ext_vector_type(8))) short bf16x8;
typedef __attribute__((ext_vector_type(4))) float f32x4;

// bf16 activation / weight buffers (static to avoid ws_size dependence)
static __device__ unsigned short g_xbf[(size_t)BATCH * ISZ];   // x in bf16
static __device__ unsigned short g_ha [(size_t)BATCH * HSZ];   // h0 (bf16)
static __device__ unsigned short g_hb [(size_t)BATCH * HSZ];   // h1 (bf16)
static __device__ float          g_h2f[(size_t)BATCH * HSZ];   // new_h fp32
static __device__ unsigned short g_Wc [2048 * KC];             // [Wih | Whh] bf16 [2048][768]
static __device__ unsigned short g_W1p[HSZ * HSZ];             // W1 in MFMA-fragment order
static __device__ unsigned short g_W2p[HSZ * HSZ];             // W2 in MFMA-fragment order

__device__ __forceinline__ unsigned short f2bf(float f) {
    unsigned int u = __float_as_uint(f);
    u += 0x7fff + ((u >> 16) & 1);   // RNE
    return (unsigned short)(u >> 16);
}
__device__ __forceinline__ float bf2f(unsigned short s) {
    return __uint_as_float((unsigned int)s << 16);
}
__device__ __forceinline__ float fsigm(float x) { return 1.0f / (1.0f + __expf(-x)); }
__device__ __forceinline__ float ftanh(float x) { return 1.0f - 2.0f / (__expf(2.0f * x) + 1.0f); }

__device__ __forceinline__ void gload16(const void* g, void* l) {
    __builtin_amdgcn_global_load_lds(
        (const __attribute__((address_space(1))) unsigned int*)g,
        (__attribute__((address_space(3))) unsigned int*)l, 16, 0, 0);
}

// ---------------------------------------------------------------------------
// fp32 -> bf16 conversion (float4-vectorized, row restride for Wih|Whh concat)
// DST: 0=g_xbf 1=g_ha 2=g_Wc
// ---------------------------------------------------------------------------
template <int DST>
__global__ __launch_bounds__(256) void conv_kernel(
    const float* __restrict__ src, int nv, int w4shift, int dstride, int doff)
{
    unsigned short* __restrict__ dst = DST == 0 ? g_xbf : DST == 1 ? g_ha : g_Wc;
    int i = blockIdx.x * 256 + threadIdx.x;
    const int gs = gridDim.x * 256;
    for (; i < nv; i += gs) {
        const int r = i >> w4shift;
        const int c = i & ((1 << w4shift) - 1);
        const float4 v = ((const float4*)src)[i];
        ushort4 o;
        o.x = f2bf(v.x); o.y = f2bf(v.y); o.z = f2bf(v.z); o.w = f2bf(v.w);
        *(ushort4*)&dst[(size_t)r * dstride + doff + c * 4] = o;
    }
}

// ---------------------------------------------------------------------------
// W1/W2 -> MFMA fragment order: chunk c = fb*1024 + st*64 + lq*16 + l15:
//   W'[c*8 + e] = W[fb*16+l15][st*32 + lq*8 + e]
// Fragment (fb, st) for lane l contiguous at W' + (fb*16+st)*512 + l*8 (1KB).
// ---------------------------------------------------------------------------
template <int DST>   // 0 -> g_W1p, 1 -> g_W2p
__global__ __launch_bounds__(256) void conv_fragW(const float* __restrict__ src)
{
    unsigned short* __restrict__ dst = DST == 0 ? g_W1p : g_W2p;
    const int c = blockIdx.x * 256 + threadIdx.x;   // 32768 chunks
    const int l15 = c & 15, lq = (c >> 4) & 3, st = (c >> 6) & 15, fb = c >> 10;
    const int n = fb * 16 + l15;
    const int k = st * 32 + lq * 8;
    const float4 v0 = *(const float4*)&src[(size_t)n * HSZ + k];
    const float4 v1 = *(const float4*)&src[(size_t)n * HSZ + k + 4];
    unsigned short o[8] = {f2bf(v0.x), f2bf(v0.y), f2bf(v0.z), f2bf(v0.w),
                           f2bf(v1.x), f2bf(v1.y), f2bf(v1.z), f2bf(v1.w)};
    *(bf16x8*)&dst[(size_t)c * 8] = *(bf16x8*)o;
}

// ---------------------------------------------------------------------------
// LSTM cell MFMA GEMM, SINGLE-buffered (m97-style): 128x128 tile, BK=64,
// 4 waves, 32KB LDS -> ~5 blocks/CU, relying on cross-block implicit overlap
// (m114) to hide the per-iter vmcnt(0) drain. 1D grid with bijective XCD
// swizzle, n-chunk fastest (A-panel L2 reuse, R4-proven).
// MODE 0: h1 -> g_hb (bf16).  MODE 1: h2 -> g_h2f (fp32).
// ---------------------------------------------------------------------------
template <int MODE>
__global__ __launch_bounds__(256) void cell_kernel(
    const float* __restrict__ bih, const float* __restrict__ bhh,
    const float* __restrict__ c_in, float* __restrict__ c_out)
{
    constexpr int NKT = KC / 64;   // 12
    constexpr int NCH = 16;

    __shared__ __align__(16) unsigned short As[128 * 64];
    __shared__ __align__(16) unsigned short Bs[128 * 64];

    const int orig = blockIdx.x;
    const int q = gridDim.x >> 3;
    const int wg = (orig & 7) * q + (orig >> 3);
    const int nbc = wg % NCH;
    const int mBase = (wg / NCH) * 128;

    const int tid  = threadIdx.x;
    const int lane = tid & 63;
    const int wid  = tid >> 6;
    const int wr   = wid >> 1, wc = wid & 1;
    const int l15  = lane & 15, lq = lane >> 4;

    const unsigned short* __restrict__ Ah = (MODE == 0) ? g_ha : g_hb;

    const int arow = tid >> 3, ch = tid & 7;
    int bgrow[4];
#pragma unroll
    for (int j = 0; j < 4; ++j) {
        const int vr = j * 32 + arow;
        const int g    = (vr >> 4) & 3;
        const int jcol = nbc * 32 + (vr >> 6) * 16 + (vr & 15);
        bgrow[j] = g * 512 + jcol;
    }

    f32x4 acc[4][4];
#pragma unroll
    for (int fm = 0; fm < 4; ++fm)
#pragma unroll
        for (int fn = 0; fn < 4; ++fn) acc[fm][fn] = (f32x4){0.f, 0.f, 0.f, 0.f};

    for (int kt = 0; kt < NKT; ++kt) {
        const int k0 = kt * 64;
#pragma unroll
        for (int j = 0; j < 4; ++j) {
            const int row = j * 32 + arow;
            const unsigned short* ga = (k0 < 256)
                ? g_xbf + (size_t)(mBase + row) * ISZ + (k0       + ch * 8)
                : Ah    + (size_t)(mBase + row) * HSZ + (k0 - 256 + ch * 8);
            gload16(ga, (char*)As + j * 4096 + wid * 1024);
            const unsigned short* gb = g_Wc + (size_t)bgrow[j] * KC + k0 + ch * 8;
            gload16(gb, (char*)Bs + j * 4096 + wid * 1024);
        }
        __syncthreads();
#pragma unroll
        for (int kk = 0; kk < 2; ++kk) {
            bf16x8 a[4], b[4];
#pragma unroll
            for (int f = 0; f < 4; ++f) {
                const int rowA = wr * 64 + f * 16 + l15;
                a[f] = *(const bf16x8*)((const char*)As + rowA * 128 + kk * 64 + lq * 16);
                const int rowB = wc * 64 + f * 16 + l15;
                b[f] = *(const bf16x8*)((const char*)Bs + rowB * 128 + kk * 64 + lq * 16);
            }
#pragma unroll
            for (int fm = 0; fm < 4; ++fm)
#pragma unroll
                for (int fn = 0; fn < 4; ++fn)
                    acc[fm][fn] = __builtin_amdgcn_mfma_f32_16x16x32_bf16(
                        a[fm], b[fn], acc[fm][fn], 0, 0, 0);
        }
        __syncthreads();
    }

    const int j = nbc * 32 + wc * 16 + l15;
    float bsum[4];
#pragma unroll
    for (int g = 0; g < 4; ++g) bsum[g] = bih[g * 512 + j] + bhh[g * 512 + j];
#pragma unroll
    for (int fm = 0; fm < 4; ++fm) {
#pragma unroll
        for (int r = 0; r < 4; ++r) {
            const int m = mBase + wr * 64 + fm * 16 + lq * 4 + r;
            const size_t idx = (size_t)m * HSZ + j;
            const float ig = fsigm(acc[fm][0][r] + bsum[0]);
            const float fg = fsigm(acc[fm][1][r] + bsum[1]);
            const float gg = ftanh(acc[fm][2][r] + bsum[2]);
            const float og = fsigm(acc[fm][3][r] + bsum[3]);
            const float cnew = fg * c_in[idx] + ig * gg;
            const float hnew = og * ftanh(cnew);
            c_out[idx] = cnew;
            if constexpr (MODE == 0) g_hb[idx] = f2bf(hnew);
            else                     g_h2f[idx] = hnew;
        }
    }
}

// ---------------------------------------------------------------------------
// Fully-fused RK4 — EXACT R11 version (proven 325us, VGPR 128, no spill).
// Block = 32 rows x 512 threads (8 waves), wave owns 32x64 (2m x 4n frags).
// Pipelined do_gemm with static b0/b1 full-step prefetch + sched_barrier.
// LDS: sU 32KB (htmp/u, XOR-swizzled) + sH 32KB (h2 bf16).
// ---------------------------------------------------------------------------
__global__ __launch_bounds__(512, 1) void rk_fused_kernel(
    const float* __restrict__ ts, const float* __restrict__ b1,
    const float* __restrict__ b2, float* __restrict__ out_ht)
{
    __shared__ __align__(16) unsigned short sU[32 * 512];   // 32 KB
    __shared__ __align__(16) unsigned short sH[32 * 512];   // 32 KB

    const int tid = threadIdx.x, lane = tid & 63;
    const int w = tid >> 6;                  // wave -> 64-col chunk
    const int l15 = lane & 15, lq = lane >> 4;
    const int nb = w * 64;
    const int m0 = blockIdx.x * 32;

    float b1v[4], b2v[4];
#pragma unroll
    for (int fn = 0; fn < 4; ++fn) {
        b1v[fn] = b1[nb + fn * 16 + l15];
        b2v[fn] = b2[nb + fn * 16 + l15];
    }

    // init: coalesced float4 read of h2, seed sU (htmp) and sH (h2 bf16)
    {
        const float4* __restrict__ src = (const float4*)(g_h2f + (size_t)m0 * HSZ);
#pragma unroll
        for (int i = 0; i < 8; ++i) {
            const int flat = i * 512 + tid;       // float4 index in 32x128
            const int row = flat >> 7;
            const int c4 = flat & 127;
            const float4 v = src[flat];
            ushort4 o;
            o.x = f2bf(v.x); o.y = f2bf(v.y); o.z = f2bf(v.z); o.w = f2bf(v.w);
            const int off = row * 1024 + ((c4 * 8) ^ ((row & 7) << 4));
            *(ushort4*)((char*)sU + off) = o;
            *(ushort4*)((char*)sH + off) = o;
        }
    }
    __syncthreads();

    f32x4 rk[2][4];
#pragma unroll
    for (int fm = 0; fm < 2; ++fm)
#pragma unroll
        for (int fn = 0; fn < 4; ++fn) rk[fm][fn] = (f32x4){0.f, 0.f, 0.f, 0.f};

    // fragment loaders
    auto loadB = [&](bf16x8 (&bb)[4], const unsigned short* __restrict__ Wp, int st) {
#pragma unroll
        for (int f = 0; f < 4; ++f)
            bb[f] = *(const bf16x8*)(Wp + (size_t)(((w * 4 + f) * 16 + st) * 512 + lane * 8));
    };
    auto loadA = [&](bf16x8 (&aa)[2], int st) {
#pragma unroll
        for (int f = 0; f < 2; ++f) {
            const int row = f * 16 + l15;
            aa[f] = *(const bf16x8*)((const char*)sU + row * 1024 +
                                     ((st * 64 + lq * 16) ^ ((l15 & 7) << 4)));
        }
    };

    auto do_gemm = [&](const unsigned short* __restrict__ Wp, f32x4 (&gacc)[2][4]) {
#pragma unroll
        for (int fm = 0; fm < 2; ++fm)
#pragma unroll
            for (int fn = 0; fn < 4; ++fn) gacc[fm][fn] = (f32x4){0.f, 0.f, 0.f, 0.f};
        bf16x8 b0[4], b1f[4], a[2];
        loadB(b0, Wp, 0);
#pragma unroll 1
        for (int st = 0; st < 16; st += 2) {
            loadB(b1f, Wp, st + 1);
            loadA(a, st);
#pragma unroll
            for (int fm = 0; fm < 2; ++fm)
#pragma unroll
                for (int fn = 0; fn < 4; ++fn)
                    gacc[fm][fn] = __builtin_amdgcn_mfma_f32_16x16x32_bf16(
                        a[fm], b0[fn], gacc[fm][fn], 0, 0, 0);
            __builtin_amdgcn_sched_barrier(0);
            if (st + 2 < 16) loadB(b0, Wp, st + 2);
            loadA(a, st + 1);
#pragma unroll
            for (int fm = 0; fm < 2; ++fm)
#pragma unroll
                for (int fn = 0; fn < 4; ++fn)
                    gacc[fm][fn] = __builtin_amdgcn_mfma_f32_16x16x32_bf16(
                        a[fm], b1f[fn], gacc[fm][fn], 0, 0, 0);
            __builtin_amdgcn_sched_barrier(0);
        }
    };

#pragma unroll 1
    for (int s = 0; s < 4; ++s) {
        f32x4 gacc[2][4];
        // GEMM1: u = tanh(htmp @ W1^T + b1)
        do_gemm(g_W1p, gacc);
        __syncthreads();                      // htmp reads complete
#pragma unroll
        for (int fm = 0; fm < 2; ++fm)
#pragma unroll
            for (int fn = 0; fn < 4; ++fn)
#pragma unroll
                for (int r = 0; r < 4; ++r) {
                    const int row = fm * 16 + lq * 4 + r;
                    const int col = nb + fn * 16 + l15;
                    *(unsigned short*)((char*)sU + row * 1024 +
                                       ((col * 2) ^ ((row & 7) << 4))) =
                        f2bf(ftanh(gacc[fm][fn][r] + b1v[fn]));
                }
        __syncthreads();
        // GEMM2: k = u @ W2^T + b2
        do_gemm(g_W2p, gacc);
        __syncthreads();                      // u reads complete
        const float wk = (s == 1 || s == 2) ? 2.0f : 1.0f;
        const float cs = (s == 2) ? 1.0f : 0.5f;
#pragma unroll
        for (int fm = 0; fm < 2; ++fm) {
            float dtf[4];
#pragma unroll
            for (int r = 0; r < 4; ++r) {
                const int m = m0 + fm * 16 + lq * 4 + r;
                const float2 tv = *(const float2*)&ts[2 * m];
                dtf[r] = tv.y - tv.x;
            }
#pragma unroll
            for (int fn = 0; fn < 4; ++fn)
#pragma unroll
                for (int r = 0; r < 4; ++r) {
                    const int row = fm * 16 + lq * 4 + r;
                    const int col = nb + fn * 16 + l15;
                    const float kv = gacc[fm][fn][r] + b2v[fn];
                    rk[fm][fn][r] += wk * kv;
                    if (s < 3) {
                        const int off = row * 1024 + ((col * 2) ^ ((row & 7) << 4));
                        const float h2 = bf2f(*(const unsigned short*)((const char*)sH + off));
                        *(unsigned short*)((char*)sU + off) = f2bf(h2 + cs * dtf[r] * kv);
                    } else {
                        const size_t idx = (size_t)(m0 + row) * HSZ + col;
                        out_ht[idx] = g_h2f[idx] + dtf[r] * (1.0f / 6.0f) * rk[fm][fn][r];
                    }
                }
        }
        if (s < 3) __syncthreads();
    }
}

extern "C" void kernel_launch(void* const* d_in, const int* in_sizes, int n_in,
                              void* d_out, int out_size, void* d_ws, size_t ws_size,
                              hipStream_t stream) {
    const float* x   = (const float*)d_in[0];
    const float* h0  = (const float*)d_in[1];
    const float* c0  = (const float*)d_in[2];
    const float* ts  = (const float*)d_in[3];
    const float* Wih = (const float*)d_in[4];
    const float* Whh = (const float*)d_in[5];
    const float* bih = (const float*)d_in[6];
    const float* bhh = (const float*)d_in[7];
    const float* W1  = (const float*)d_in[8];
    const float* b1  = (const float*)d_in[9];
    const float* W2  = (const float*)d_in[10];
    const float* b2  = (const float*)d_in[11];

    float* out_ht = (float*)d_out;
    float* out_c  = out_ht + (size_t)BATCH * HSZ;

    dim3 blk(256);
    conv_kernel<0><<<2048, blk, 0, stream>>>(x,   BATCH * ISZ / 4, 6, ISZ, 0);
    conv_kernel<1><<<2048, blk, 0, stream>>>(h0,  BATCH * HSZ / 4, 7, HSZ, 0);
    conv_kernel<2><<<256,  blk, 0, stream>>>(Wih, 2048 * 256 / 4,  6, KC, 0);
    conv_kernel<2><<<256,  blk, 0, stream>>>(Whh, 2048 * 512 / 4,  7, KC, 256);
    conv_fragW<0><<<128,  blk, 0, stream>>>(W1);
    conv_fragW<1><<<128,  blk, 0, stream>>>(W2);

    dim3 gcell(BATCH / 128 * 16);  // 4096 blocks: 16 n-chunks x 256 m-panels

    cell_kernel<0><<<gcell, blk, 0, stream>>>(bih, bhh, c0,    out_c);
    cell_kernel<1><<<gcell, blk, 0, stream>>>(bih, bhh, out_c, out_c);

    rk_fused_kernel<<<BATCH / 32, 512, 0, stream>>>(ts, b1, b2, out_ht);
}